// Round 4
// baseline (318.745 us; speedup 1.0000x reference)
//
#include <hip/hip_runtime.h>

// Kalman-style linear recurrence, exact chunked-scan parallelization.
//   M = A - L*H ;  x_{k+1} = M x_k + L y_k ;  out_k = H x_k
// C = 64 steps/chunk, P = N/64 chunks. Lookback depth 8 with P64 = M^64.
// Requires Nv % 64 == 0 (true here: 200000 = 3125*64).
//
// R6 = R5 rerun (R5 bench died on a sick node: 779s npz push, pytest core
// dump, no HIP fault text; kernel re-audited OOB/align/reg-clean).
// Theory unchanged: R4 counters showed VGPR 112, occupancy ~1.3 waves/SIMD,
// VALUBusy 45%, per-step period ~1150cyc vs ~400cyc issue -> per-wave ILP
// is the bottleneck, not issue count. Each wave advances TWO independent
// chunks (G=2) sharing Mrow/Hrow; broadcast x[j] via v_readlane_b32
// (compile-time lane idx) -> no LDS, no barrier in the main loop.
// Defensive delta vs R5: phase1 launch_bounds (64,3)->(64,2) (residency is
// grid-limited anyway; removes the 168-reg cap).

#define CHUNK 64
#define LOOKBACK 8

__device__ __forceinline__ float bcast(float x, int l) {
  return __uint_as_float(__builtin_amdgcn_readlane(__float_as_uint(x), l));
}

// ---------------------------------------------------------------- setup ----
__global__ __launch_bounds__(1024) void kf_setup(const float* __restrict__ A,
                                                 const float* __restrict__ Hm,
                                                 const float* __restrict__ Lp,
                                                 float* __restrict__ ws) {
  __shared__ __align__(16) float s0[64 * 68];
  __shared__ __align__(16) float s1[64 * 68];
  const float Lg = Lp[0];
  const int t  = threadIdx.x;      // 0..1023
  const int r  = t >> 4;           // 0..63
  const int c0 = (t & 15) * 4;     // 0,4,..,60

  // zero pad region ws[4096 .. 4607] (lookback reads b[c<0] as 0)
  if (t < 512) ws[4096 + t] = 0.f;

  {
    const float4 a4 = *(const float4*)(A  + r * 64 + c0);
    const float4 h4 = *(const float4*)(Hm + r * 64 + c0);
    float4 m4;
    m4.x = fmaf(-Lg, h4.x, a4.x);
    m4.y = fmaf(-Lg, h4.y, a4.y);
    m4.z = fmaf(-Lg, h4.z, a4.z);
    m4.w = fmaf(-Lg, h4.w, a4.w);
    *(float4*)(s0 + r * 68 + c0) = m4;
  }
  __syncthreads();

  float* src = s0;
  float* dst = s1;
  for (int sq = 0; sq < 6; ++sq) {           // M^2, M^4, ... M^64
    float4 acc = make_float4(0.f, 0.f, 0.f, 0.f);
    const float* srow = src + r * 68;
    #pragma unroll 8
    for (int k = 0; k < 64; ++k) {
      const float  a  = srow[k];
      const float4 b4 = *(const float4*)(src + k * 68 + c0);
      acc.x = fmaf(a, b4.x, acc.x);
      acc.y = fmaf(a, b4.y, acc.y);
      acc.z = fmaf(a, b4.z, acc.z);
      acc.w = fmaf(a, b4.w, acc.w);
    }
    __syncthreads();
    *(float4*)(dst + r * 68 + c0) = acc;
    __syncthreads();
    float* tmp = src; src = dst; dst = tmp;
  }
  *(float4*)(ws + r * 64 + c0) = *(const float4*)(src + r * 68 + c0);
}

// --------------------------------------------------------------- phase 1 ----
// G=2 chunks per 1-wave block; readlane broadcast; 2 accs per dot.
__global__ __launch_bounds__(64, 2) void kf_phase1(const float* __restrict__ y,
                                                   const float* __restrict__ A,
                                                   const float* __restrict__ Hm,
                                                   const float* __restrict__ Lp,
                                                   float* __restrict__ bb,
                                                   int Nv, int P) {
  const int lane = threadIdx.x;
  const float Lg = Lp[0];
  const int c0 = min(2 * (int)blockIdx.x,     P - 1);
  const int c1 = min(2 * (int)blockIdx.x + 1, P - 1);   // clamp: same-wave duplicate, benign

  float Mrow[64];
  {
    const float* Ar = A  + lane * 64;
    const float* Hr = Hm + lane * 64;
    #pragma unroll
    for (int j = 0; j < 64; j += 4) {
      const float4 a4 = *(const float4*)(Ar + j);
      const float4 h4 = *(const float4*)(Hr + j);
      Mrow[j + 0] = fmaf(-Lg, h4.x, a4.x);
      Mrow[j + 1] = fmaf(-Lg, h4.y, a4.y);
      Mrow[j + 2] = fmaf(-Lg, h4.z, a4.z);
      Mrow[j + 3] = fmaf(-Lg, h4.w, a4.w);
    }
  }

  const float* yr0 = y + (size_t)lane * (size_t)Nv + c0 * CHUNK;
  const float* yr1 = y + (size_t)lane * (size_t)Nv + c1 * CHUNK;
  float x0 = 0.f, x1 = 0.f;

  #pragma unroll 1
  for (int t = 0; t < 8; ++t) {
    const float4 pa0 = *(const float4*)(yr0 + 8 * t);
    const float4 pb0 = *(const float4*)(yr0 + 8 * t + 4);
    const float4 pa1 = *(const float4*)(yr1 + 8 * t);
    const float4 pb1 = *(const float4*)(yr1 + 8 * t + 4);
    const float yb0[8] = {pa0.x, pa0.y, pa0.z, pa0.w, pb0.x, pb0.y, pb0.z, pb0.w};
    const float yb1[8] = {pa1.x, pa1.y, pa1.z, pa1.w, pb1.x, pb1.y, pb1.z, pb1.w};
    #pragma unroll
    for (int kk = 0; kk < 8; ++kk) {
      float a0 = 0.f, a1 = 0.f, b0 = 0.f, b1 = 0.f;
      #pragma unroll
      for (int j = 0; j < 64; j += 2) {
        const float s0 = bcast(x0, j);
        const float s1 = bcast(x1, j);
        const float u0 = bcast(x0, j + 1);
        const float u1 = bcast(x1, j + 1);
        a0 = fmaf(Mrow[j],     s0, a0);
        b0 = fmaf(Mrow[j],     s1, b0);
        a1 = fmaf(Mrow[j + 1], u0, a1);
        b1 = fmaf(Mrow[j + 1], u1, b1);
      }
      x0 = fmaf(Lg, yb0[kk], a0 + a1);
      x1 = fmaf(Lg, yb1[kk], b0 + b1);
    }
  }
  bb[c0 * 64 + lane] = x0;
  bb[c1 * 64 + lane] = x1;
}

// --------------------------------------------------------------- phase 3 ----
// G=2 chunks per 1-wave block; one readlane pair feeds H- and M-dots of
// both chunks (128 rl + 256 fma per time-step pair).
__global__ __launch_bounds__(64, 1) void kf_phase3(const float* __restrict__ y,
                                                   const float* __restrict__ A,
                                                   const float* __restrict__ Hm,
                                                   const float* __restrict__ Lp,
                                                   const float* __restrict__ bb,
                                                   const float* __restrict__ P64,
                                                   float* __restrict__ out,
                                                   int Nv, int P) {
  const int lane = threadIdx.x;
  const float Lg = Lp[0];
  const int c0 = min(2 * (int)blockIdx.x,     P - 1);
  const int c1 = min(2 * (int)blockIdx.x + 1, P - 1);

  float Mrow[64];
  {
    const float* Ar = A  + lane * 64;
    const float* Hr = Hm + lane * 64;
    #pragma unroll
    for (int j = 0; j < 64; j += 4) {
      const float4 a4 = *(const float4*)(Ar + j);
      const float4 h4 = *(const float4*)(Hr + j);
      Mrow[j + 0] = fmaf(-Lg, h4.x, a4.x);
      Mrow[j + 1] = fmaf(-Lg, h4.y, a4.y);
      Mrow[j + 2] = fmaf(-Lg, h4.z, a4.z);
      Mrow[j + 3] = fmaf(-Lg, h4.w, a4.w);
    }
  }

  // ---- lookback, uniform depth 8 (bb has 512-float zero pad in front):
  //      s_c = b[c-1] + P64*(b[c-2] + P64*(... b[c-8]))
  float x0, x1;
  {
    float Prow[64];  // lifetime ends before Hrow loads; allocator reuses
    #pragma unroll
    for (int j = 0; j < 64; j += 4) {
      const float4 p4 = *(const float4*)(P64 + lane * 64 + j);
      Prow[j + 0] = p4.x; Prow[j + 1] = p4.y;
      Prow[j + 2] = p4.z; Prow[j + 3] = p4.w;
    }
    x0 = bb[(c0 - LOOKBACK) * 64 + lane];
    x1 = bb[(c1 - LOOKBACK) * 64 + lane];
    #pragma unroll 1
    for (int t = LOOKBACK - 1; t >= 1; --t) {
      float a0 = 0.f, a1 = 0.f, b0 = 0.f, b1 = 0.f;
      #pragma unroll
      for (int j = 0; j < 64; j += 2) {
        const float s0 = bcast(x0, j);
        const float s1 = bcast(x1, j);
        const float u0 = bcast(x0, j + 1);
        const float u1 = bcast(x1, j + 1);
        a0 = fmaf(Prow[j],     s0, a0);
        b0 = fmaf(Prow[j],     s1, b0);
        a1 = fmaf(Prow[j + 1], u0, a1);
        b1 = fmaf(Prow[j + 1], u1, b1);
      }
      x0 = (a0 + a1) + bb[(c0 - t) * 64 + lane];
      x1 = (b0 + b1) + bb[(c1 - t) * 64 + lane];
    }
  }

  float Hrow[64];
  #pragma unroll
  for (int j = 0; j < 64; j += 4) {
    const float4 h4 = *(const float4*)(Hm + lane * 64 + j);
    Hrow[j + 0] = h4.x; Hrow[j + 1] = h4.y;
    Hrow[j + 2] = h4.z; Hrow[j + 3] = h4.w;
  }

  const float* yr0 = y   + (size_t)lane * (size_t)Nv + c0 * CHUNK;
  const float* yr1 = y   + (size_t)lane * (size_t)Nv + c1 * CHUNK;
  float*       o0  = out + (size_t)lane * (size_t)Nv + c0 * CHUNK;
  float*       o1  = out + (size_t)lane * (size_t)Nv + c1 * CHUNK;

  #pragma unroll 1
  for (int t = 0; t < 8; ++t) {
    const float4 pa0 = *(const float4*)(yr0 + 8 * t);
    const float4 pb0 = *(const float4*)(yr0 + 8 * t + 4);
    const float4 pa1 = *(const float4*)(yr1 + 8 * t);
    const float4 pb1 = *(const float4*)(yr1 + 8 * t + 4);
    const float yb0[8] = {pa0.x, pa0.y, pa0.z, pa0.w, pb0.x, pb0.y, pb0.z, pb0.w};
    const float yb1[8] = {pa1.x, pa1.y, pa1.z, pa1.w, pb1.x, pb1.y, pb1.z, pb1.w};
    float ob0[8], ob1[8];

    #pragma unroll
    for (int kk = 0; kk < 8; ++kk) {
      float h0a = 0.f, h0b = 0.f, m0a = 0.f, m0b = 0.f;
      float h1a = 0.f, h1b = 0.f, m1a = 0.f, m1b = 0.f;
      #pragma unroll
      for (int j = 0; j < 64; j += 2) {
        const float s0 = bcast(x0, j);
        const float s1 = bcast(x1, j);
        const float u0 = bcast(x0, j + 1);
        const float u1 = bcast(x1, j + 1);
        h0a = fmaf(Hrow[j],     s0, h0a);
        m0a = fmaf(Mrow[j],     s0, m0a);
        h1a = fmaf(Hrow[j],     s1, h1a);
        m1a = fmaf(Mrow[j],     s1, m1a);
        h0b = fmaf(Hrow[j + 1], u0, h0b);
        m0b = fmaf(Mrow[j + 1], u0, m0b);
        h1b = fmaf(Hrow[j + 1], u1, h1b);
        m1b = fmaf(Mrow[j + 1], u1, m1b);
      }
      ob0[kk] = h0a + h0b;
      ob1[kk] = h1a + h1b;
      x0 = fmaf(Lg, yb0[kk], m0a + m0b);
      x1 = fmaf(Lg, yb1[kk], m1a + m1b);
    }
    *(float4*)(o0 + 8 * t)     = make_float4(ob0[0], ob0[1], ob0[2], ob0[3]);
    *(float4*)(o0 + 8 * t + 4) = make_float4(ob0[4], ob0[5], ob0[6], ob0[7]);
    *(float4*)(o1 + 8 * t)     = make_float4(ob1[0], ob1[1], ob1[2], ob1[3]);
    *(float4*)(o1 + 8 * t + 4) = make_float4(ob1[4], ob1[5], ob1[6], ob1[7]);
  }
}

// ---------------------------------------------------------------------------
extern "C" void kernel_launch(void* const* d_in, const int* in_sizes, int n_in,
                              void* d_out, int out_size, void* d_ws, size_t ws_size,
                              hipStream_t stream) {
  const float* y  = (const float*)d_in[0];
  const float* A  = (const float*)d_in[1];
  const float* Hm = (const float*)d_in[2];
  const float* Lp = (const float*)d_in[3];
  const int Nv = in_sizes[0] / 64;          // 200000 (multiple of 64)
  const int P  = (Nv + CHUNK - 1) / CHUNK;  // 3125
  const int B2 = (P + 1) / 2;               // G=2 blocks

  float* ws   = (float*)d_ws;
  float* P64  = ws;                  // 4096 floats
  float* bb   = ws + 4096 + 512;     // bvec; 512-float zero pad in front

  kf_setup<<<1, 1024, 0, stream>>>(A, Hm, Lp, ws);
  kf_phase1<<<B2, 64, 0, stream>>>(y, A, Hm, Lp, bb, Nv, P);
  kf_phase3<<<B2, 64, 0, stream>>>(y, A, Hm, Lp, bb, P64, (float*)d_out, Nv, P);
}

// Round 5
// 279.901 us; speedup vs baseline: 1.1388x; 1.1388x over previous
//
#include <hip/hip_runtime.h>

// Kalman-style linear recurrence, exact chunked-scan parallelization.
//   M = A - L*H ;  x_{k+1} = M x_k + L y_k ;  out_k = H x_k
// C = 64 steps/chunk, P = N/64 chunks. Lookback depth 8 with P64 = M^64.
// Requires Nv % 64 == 0 (true here: 200000 = 3125*64).
//
// R7: H-deferral. R6 evidence: G=2 wins when live set is small (phase1
// 140->95us) and loses when it blows the 256-VGPR wall (phase3 107->215,
// VGPR 136 => AGPR/scratch shuffling). So remove H from the scan entirely:
// scan2 stores pre-update states x_k into d_out; a separate throughput
// kernel computes out = H @ X in place (coalesced column loads, uniform
// H rows via scalar loads, no broadcasts, no recurrence). phase1 goes G=4
// (live ~120 fits). Scan work per step drops from 192 ops to 128, and the
// H-half of the old phase3 now runs at issue rate instead of latency rate.

#define CHUNK 64
#define LOOKBACK 8

__device__ __forceinline__ float bcast(float x, int l) {
  return __uint_as_float(__builtin_amdgcn_readlane(__float_as_uint(x), l));
}

// ---------------------------------------------------------------- setup ----
__global__ __launch_bounds__(1024) void kf_setup(const float* __restrict__ A,
                                                 const float* __restrict__ Hm,
                                                 const float* __restrict__ Lp,
                                                 float* __restrict__ ws) {
  __shared__ __align__(16) float s0[64 * 68];
  __shared__ __align__(16) float s1[64 * 68];
  const float Lg = Lp[0];
  const int t  = threadIdx.x;      // 0..1023
  const int r  = t >> 4;           // 0..63
  const int c0 = (t & 15) * 4;     // 0,4,..,60

  // zero pad region ws[4096 .. 4607] (lookback reads b[c<0] as 0)
  if (t < 512) ws[4096 + t] = 0.f;

  {
    const float4 a4 = *(const float4*)(A  + r * 64 + c0);
    const float4 h4 = *(const float4*)(Hm + r * 64 + c0);
    float4 m4;
    m4.x = fmaf(-Lg, h4.x, a4.x);
    m4.y = fmaf(-Lg, h4.y, a4.y);
    m4.z = fmaf(-Lg, h4.z, a4.z);
    m4.w = fmaf(-Lg, h4.w, a4.w);
    *(float4*)(s0 + r * 68 + c0) = m4;
  }
  __syncthreads();

  float* src = s0;
  float* dst = s1;
  for (int sq = 0; sq < 6; ++sq) {           // M^2, M^4, ... M^64
    float4 acc = make_float4(0.f, 0.f, 0.f, 0.f);
    const float* srow = src + r * 68;
    #pragma unroll 8
    for (int k = 0; k < 64; ++k) {
      const float  a  = srow[k];
      const float4 b4 = *(const float4*)(src + k * 68 + c0);
      acc.x = fmaf(a, b4.x, acc.x);
      acc.y = fmaf(a, b4.y, acc.y);
      acc.z = fmaf(a, b4.z, acc.z);
      acc.w = fmaf(a, b4.w, acc.w);
    }
    __syncthreads();
    *(float4*)(dst + r * 68 + c0) = acc;
    __syncthreads();
    float* tmp = src; src = dst; dst = tmp;
  }
  *(float4*)(ws + r * 64 + c0) = *(const float4*)(src + r * 68 + c0);
}

// --------------------------------------------------------------- phase 1 ----
// G=4 chunks per 1-wave block; readlane broadcast; live ~120 VGPR.
__global__ __launch_bounds__(64, 2) void kf_phase1(const float* __restrict__ y,
                                                   const float* __restrict__ A,
                                                   const float* __restrict__ Hm,
                                                   const float* __restrict__ Lp,
                                                   float* __restrict__ bb,
                                                   int Nv, int P) {
  const int lane = threadIdx.x;
  const float Lg = Lp[0];
  const int c0 = min(4 * (int)blockIdx.x + 0, P - 1);
  const int c1 = min(4 * (int)blockIdx.x + 1, P - 1);
  const int c2 = min(4 * (int)blockIdx.x + 2, P - 1);
  const int c3 = min(4 * (int)blockIdx.x + 3, P - 1);  // clamp: same-wave dup, benign

  float Mrow[64];
  {
    const float* Ar = A  + lane * 64;
    const float* Hr = Hm + lane * 64;
    #pragma unroll
    for (int j = 0; j < 64; j += 4) {
      const float4 a4 = *(const float4*)(Ar + j);
      const float4 h4 = *(const float4*)(Hr + j);
      Mrow[j + 0] = fmaf(-Lg, h4.x, a4.x);
      Mrow[j + 1] = fmaf(-Lg, h4.y, a4.y);
      Mrow[j + 2] = fmaf(-Lg, h4.z, a4.z);
      Mrow[j + 3] = fmaf(-Lg, h4.w, a4.w);
    }
  }

  const float* yr0 = y + (size_t)lane * (size_t)Nv + c0 * CHUNK;
  const float* yr1 = y + (size_t)lane * (size_t)Nv + c1 * CHUNK;
  const float* yr2 = y + (size_t)lane * (size_t)Nv + c2 * CHUNK;
  const float* yr3 = y + (size_t)lane * (size_t)Nv + c3 * CHUNK;
  float x0 = 0.f, x1 = 0.f, x2 = 0.f, x3 = 0.f;

  #pragma unroll 1
  for (int t = 0; t < 8; ++t) {
    const float4 pa0 = *(const float4*)(yr0 + 8 * t);
    const float4 pb0 = *(const float4*)(yr0 + 8 * t + 4);
    const float4 pa1 = *(const float4*)(yr1 + 8 * t);
    const float4 pb1 = *(const float4*)(yr1 + 8 * t + 4);
    const float4 pa2 = *(const float4*)(yr2 + 8 * t);
    const float4 pb2 = *(const float4*)(yr2 + 8 * t + 4);
    const float4 pa3 = *(const float4*)(yr3 + 8 * t);
    const float4 pb3 = *(const float4*)(yr3 + 8 * t + 4);
    const float yb0[8] = {pa0.x, pa0.y, pa0.z, pa0.w, pb0.x, pb0.y, pb0.z, pb0.w};
    const float yb1[8] = {pa1.x, pa1.y, pa1.z, pa1.w, pb1.x, pb1.y, pb1.z, pb1.w};
    const float yb2[8] = {pa2.x, pa2.y, pa2.z, pa2.w, pb2.x, pb2.y, pb2.z, pb2.w};
    const float yb3[8] = {pa3.x, pa3.y, pa3.z, pa3.w, pb3.x, pb3.y, pb3.z, pb3.w};
    #pragma unroll
    for (int kk = 0; kk < 8; ++kk) {
      float a0 = 0.f, a1 = 0.f, a2 = 0.f, a3 = 0.f;
      #pragma unroll
      for (int j = 0; j < 64; ++j) {
        const float s0 = bcast(x0, j);
        const float s1 = bcast(x1, j);
        const float s2 = bcast(x2, j);
        const float s3 = bcast(x3, j);
        a0 = fmaf(Mrow[j], s0, a0);
        a1 = fmaf(Mrow[j], s1, a1);
        a2 = fmaf(Mrow[j], s2, a2);
        a3 = fmaf(Mrow[j], s3, a3);
      }
      x0 = fmaf(Lg, yb0[kk], a0);
      x1 = fmaf(Lg, yb1[kk], a1);
      x2 = fmaf(Lg, yb2[kk], a2);
      x3 = fmaf(Lg, yb3[kk], a3);
    }
  }
  bb[c0 * 64 + lane] = x0;
  bb[c1 * 64 + lane] = x1;
  bb[c2 * 64 + lane] = x2;
  bb[c3 * 64 + lane] = x3;
}

// ---------------------------------------------------------------- scan 2 ----
// G=2 chunks per 1-wave block. Lookback-8 init, then 64 steps storing the
// PRE-update state x_k into X (= d_out) row-major. No H here -> live ~125.
__global__ __launch_bounds__(64, 2) void kf_scan2(const float* __restrict__ y,
                                                  const float* __restrict__ A,
                                                  const float* __restrict__ Hm,
                                                  const float* __restrict__ Lp,
                                                  const float* __restrict__ bb,
                                                  const float* __restrict__ P64,
                                                  float* __restrict__ X,
                                                  int Nv, int P) {
  const int lane = threadIdx.x;
  const float Lg = Lp[0];
  const int c0 = min(2 * (int)blockIdx.x,     P - 1);
  const int c1 = min(2 * (int)blockIdx.x + 1, P - 1);

  float Mrow[64];
  {
    const float* Ar = A  + lane * 64;
    const float* Hr = Hm + lane * 64;
    #pragma unroll
    for (int j = 0; j < 64; j += 4) {
      const float4 a4 = *(const float4*)(Ar + j);
      const float4 h4 = *(const float4*)(Hr + j);
      Mrow[j + 0] = fmaf(-Lg, h4.x, a4.x);
      Mrow[j + 1] = fmaf(-Lg, h4.y, a4.y);
      Mrow[j + 2] = fmaf(-Lg, h4.z, a4.z);
      Mrow[j + 3] = fmaf(-Lg, h4.w, a4.w);
    }
  }

  // ---- lookback, uniform depth 8 (bb has 512-float zero pad in front):
  //      s_c = b[c-1] + P64*(b[c-2] + P64*(... b[c-8]))
  float x0, x1;
  {
    float Prow[64];  // lifetime ends before main loop; allocator reuses
    #pragma unroll
    for (int j = 0; j < 64; j += 4) {
      const float4 p4 = *(const float4*)(P64 + lane * 64 + j);
      Prow[j + 0] = p4.x; Prow[j + 1] = p4.y;
      Prow[j + 2] = p4.z; Prow[j + 3] = p4.w;
    }
    x0 = bb[(c0 - LOOKBACK) * 64 + lane];
    x1 = bb[(c1 - LOOKBACK) * 64 + lane];
    #pragma unroll 1
    for (int t = LOOKBACK - 1; t >= 1; --t) {
      float a0 = 0.f, a1 = 0.f, b0 = 0.f, b1 = 0.f;
      #pragma unroll
      for (int j = 0; j < 64; j += 2) {
        const float s0 = bcast(x0, j);
        const float s1 = bcast(x1, j);
        const float u0 = bcast(x0, j + 1);
        const float u1 = bcast(x1, j + 1);
        a0 = fmaf(Prow[j],     s0, a0);
        b0 = fmaf(Prow[j],     s1, b0);
        a1 = fmaf(Prow[j + 1], u0, a1);
        b1 = fmaf(Prow[j + 1], u1, b1);
      }
      x0 = (a0 + a1) + bb[(c0 - t) * 64 + lane];
      x1 = (b0 + b1) + bb[(c1 - t) * 64 + lane];
    }
  }

  const float* yr0 = y + (size_t)lane * (size_t)Nv + c0 * CHUNK;
  const float* yr1 = y + (size_t)lane * (size_t)Nv + c1 * CHUNK;
  float*       X0  = X + (size_t)lane * (size_t)Nv + c0 * CHUNK;
  float*       X1  = X + (size_t)lane * (size_t)Nv + c1 * CHUNK;

  #pragma unroll 1
  for (int t = 0; t < 8; ++t) {
    const float4 pa0 = *(const float4*)(yr0 + 8 * t);
    const float4 pb0 = *(const float4*)(yr0 + 8 * t + 4);
    const float4 pa1 = *(const float4*)(yr1 + 8 * t);
    const float4 pb1 = *(const float4*)(yr1 + 8 * t + 4);
    const float yb0[8] = {pa0.x, pa0.y, pa0.z, pa0.w, pb0.x, pb0.y, pb0.z, pb0.w};
    const float yb1[8] = {pa1.x, pa1.y, pa1.z, pa1.w, pb1.x, pb1.y, pb1.z, pb1.w};
    float xb0[8], xb1[8];

    #pragma unroll
    for (int kk = 0; kk < 8; ++kk) {
      xb0[kk] = x0;                    // store PRE-update state
      xb1[kk] = x1;
      float a0 = 0.f, a1 = 0.f, b0 = 0.f, b1 = 0.f;
      #pragma unroll
      for (int j = 0; j < 64; j += 2) {
        const float s0 = bcast(x0, j);
        const float s1 = bcast(x1, j);
        const float u0 = bcast(x0, j + 1);
        const float u1 = bcast(x1, j + 1);
        a0 = fmaf(Mrow[j],     s0, a0);
        b0 = fmaf(Mrow[j],     s1, b0);
        a1 = fmaf(Mrow[j + 1], u0, a1);
        b1 = fmaf(Mrow[j + 1], u1, b1);
      }
      x0 = fmaf(Lg, yb0[kk], a0 + a1);
      x1 = fmaf(Lg, yb1[kk], b0 + b1);
    }
    *(float4*)(X0 + 8 * t)     = make_float4(xb0[0], xb0[1], xb0[2], xb0[3]);
    *(float4*)(X0 + 8 * t + 4) = make_float4(xb0[4], xb0[5], xb0[6], xb0[7]);
    *(float4*)(X1 + 8 * t)     = make_float4(xb1[0], xb1[1], xb1[2], xb1[3]);
    *(float4*)(X1 + 8 * t + 4) = make_float4(xb1[4], xb1[5], xb1[6], xb1[7]);
  }
}

// ----------------------------------------------------------------- hgemm ----
// out = H @ X, in place on d_out. Block = one 64-column chunk; lane = one
// column. Column loads/stores are coalesced (consecutive lanes -> consecutive
// addresses). H rows are wave-uniform -> scalar loads. All xcol reads happen
// before any store (single pointer xo, no restrict -> order preserved).
__global__ __launch_bounds__(64, 4) void kf_hgemm(const float* __restrict__ Hm,
                                                  float* xo, int Nv) {
  const int lane = threadIdx.x;
  const int k    = (int)blockIdx.x * CHUNK + lane;

  float xcol[64];
  #pragma unroll
  for (int r = 0; r < 64; ++r) {
    xcol[r] = xo[(size_t)r * (size_t)Nv + k];
  }

  #pragma unroll 1
  for (int r = 0; r < 64; ++r) {
    const float* hr = Hm + r * 64;
    float a0 = 0.f, a1 = 0.f;
    #pragma unroll
    for (int j = 0; j < 64; j += 2) {
      a0 = fmaf(hr[j],     xcol[j],     a0);
      a1 = fmaf(hr[j + 1], xcol[j + 1], a1);
    }
    xo[(size_t)r * (size_t)Nv + k] = a0 + a1;
  }
}

// ---------------------------------------------------------------------------
extern "C" void kernel_launch(void* const* d_in, const int* in_sizes, int n_in,
                              void* d_out, int out_size, void* d_ws, size_t ws_size,
                              hipStream_t stream) {
  const float* y  = (const float*)d_in[0];
  const float* A  = (const float*)d_in[1];
  const float* Hm = (const float*)d_in[2];
  const float* Lp = (const float*)d_in[3];
  const int Nv = in_sizes[0] / 64;          // 200000 (multiple of 64)
  const int P  = (Nv + CHUNK - 1) / CHUNK;  // 3125

  float* ws   = (float*)d_ws;
  float* P64  = ws;                  // 4096 floats
  float* bb   = ws + 4096 + 512;     // bvec; 512-float zero pad in front

  kf_setup<<<1, 1024, 0, stream>>>(A, Hm, Lp, ws);
  kf_phase1<<<(P + 3) / 4, 64, 0, stream>>>(y, A, Hm, Lp, bb, Nv, P);
  kf_scan2<<<(P + 1) / 2, 64, 0, stream>>>(y, A, Hm, Lp, bb, P64, (float*)d_out, Nv, P);
  kf_hgemm<<<P, 64, 0, stream>>>(Hm, (float*)d_out, Nv);
}

// Round 6
// 279.586 us; speedup vs baseline: 1.1401x; 1.0011x over previous
//
#include <hip/hip_runtime.h>

// Kalman-style linear recurrence, exact chunked-scan parallelization.
//   M = A - L*H ;  x_{k+1} = M x_k + L y_k ;  out_k = H x_k
// C = 64 steps/chunk, P = N/64 chunks. Lookback depth 8 with P64 = M^64.
// Requires Nv % 64 == 0 (true here: 200000 = 3125*64).
//
// R8: superposition split. R7 evidence: the scan ran TWICE (phase1 for b_c,
// scan2 for the full states) -- ~80us of duplicated serial-latency work --
// and G=4 undersubscribed the grid (782 blocks = 0.76 waves/SIMD, 83us).
// Linear recurrence => x_true_k = x_local_k + M^k s_c. So: ONE zero-init
// scan stores local states X_l (to d_out) + chunk-end b_c; a throughput
// kernel per chunk does lookback (7-step Horner), builds Z=[M^k s] by
// LOG-DEPTH doubling in LDS (6 steps, using M^(2^t) persisted by setup),
// adds X_l, and applies H with scalar-loaded rows + coalesced in-place
// stores (the proven hgemm pattern). No 64-step serial chain outside the
// single scan. Kernels 4 -> 3.
//
// ws layout (floats):
//   [t*4096,(t+1)*4096) t=0..5 : M^(2^t)  (M, M^2, M^4, M^8, M^16, M^32)
//   [6*4096, 7*4096)           : P64 = M^64
//   [7*4096, 7*4096+512)       : zero pad (lookback reads b[c<0] as 0)
//   [7*4096+512, +P*64)        : bb (chunk-end local states)

#define CHUNK 64
#define LOOKBACK 8

__device__ __forceinline__ float bcast(float x, int l) {
  return __uint_as_float(__builtin_amdgcn_readlane(__float_as_uint(x), l));
}

// ---------------------------------------------------------------- setup ----
__global__ __launch_bounds__(1024) void kf_setup(const float* __restrict__ A,
                                                 const float* __restrict__ Hm,
                                                 const float* __restrict__ Lp,
                                                 float* __restrict__ ws) {
  __shared__ __align__(16) float s0[64 * 68];
  __shared__ __align__(16) float s1[64 * 68];
  const float Lg = Lp[0];
  const int t  = threadIdx.x;      // 0..1023
  const int r  = t >> 4;           // 0..63
  const int c0 = (t & 15) * 4;     // 0,4,..,60

  if (t < 512) ws[7 * 4096 + t] = 0.f;   // bb zero pad

  {
    const float4 a4 = *(const float4*)(A  + r * 64 + c0);
    const float4 h4 = *(const float4*)(Hm + r * 64 + c0);
    float4 m4;
    m4.x = fmaf(-Lg, h4.x, a4.x);
    m4.y = fmaf(-Lg, h4.y, a4.y);
    m4.z = fmaf(-Lg, h4.z, a4.z);
    m4.w = fmaf(-Lg, h4.w, a4.w);
    *(float4*)(s0 + r * 68 + c0) = m4;
  }
  __syncthreads();

  float* src = s0;
  float* dst = s1;
  for (int sq = 0; sq < 6; ++sq) {           // square M -> ... -> M^64
    // persist M^(2^sq) before squaring
    *(float4*)(ws + sq * 4096 + r * 64 + c0) = *(const float4*)(src + r * 68 + c0);
    float4 acc = make_float4(0.f, 0.f, 0.f, 0.f);
    const float* srow = src + r * 68;
    #pragma unroll 8
    for (int k = 0; k < 64; ++k) {
      const float  a  = srow[k];
      const float4 b4 = *(const float4*)(src + k * 68 + c0);
      acc.x = fmaf(a, b4.x, acc.x);
      acc.y = fmaf(a, b4.y, acc.y);
      acc.z = fmaf(a, b4.z, acc.z);
      acc.w = fmaf(a, b4.w, acc.w);
    }
    __syncthreads();
    *(float4*)(dst + r * 68 + c0) = acc;
    __syncthreads();
    float* tmp = src; src = dst; dst = tmp;
  }
  *(float4*)(ws + 6 * 4096 + r * 64 + c0) = *(const float4*)(src + r * 68 + c0); // P64
}

// ----------------------------------------------------------------- scan ----
// The ONLY sequential kernel. G=2 chunks/wave, zero-init local scan.
// Stores pre-update local states into X (= d_out) and chunk-end state bb.
__global__ __launch_bounds__(64, 2) void kf_scan(const float* __restrict__ y,
                                                 const float* __restrict__ A,
                                                 const float* __restrict__ Hm,
                                                 const float* __restrict__ Lp,
                                                 float* __restrict__ bb,
                                                 float* __restrict__ X,
                                                 int Nv, int P) {
  const int lane = threadIdx.x;
  const float Lg = Lp[0];
  const int c0 = min(2 * (int)blockIdx.x,     P - 1);
  const int c1 = min(2 * (int)blockIdx.x + 1, P - 1);  // clamp: same-wave dup, benign

  float Mrow[64];
  {
    const float* Ar = A  + lane * 64;
    const float* Hr = Hm + lane * 64;
    #pragma unroll
    for (int j = 0; j < 64; j += 4) {
      const float4 a4 = *(const float4*)(Ar + j);
      const float4 h4 = *(const float4*)(Hr + j);
      Mrow[j + 0] = fmaf(-Lg, h4.x, a4.x);
      Mrow[j + 1] = fmaf(-Lg, h4.y, a4.y);
      Mrow[j + 2] = fmaf(-Lg, h4.z, a4.z);
      Mrow[j + 3] = fmaf(-Lg, h4.w, a4.w);
    }
  }

  const float* yr0 = y + (size_t)lane * (size_t)Nv + c0 * CHUNK;
  const float* yr1 = y + (size_t)lane * (size_t)Nv + c1 * CHUNK;
  float*       X0  = X + (size_t)lane * (size_t)Nv + c0 * CHUNK;
  float*       X1  = X + (size_t)lane * (size_t)Nv + c1 * CHUNK;
  float x0 = 0.f, x1 = 0.f;

  #pragma unroll 1
  for (int t = 0; t < 8; ++t) {
    const float4 pa0 = *(const float4*)(yr0 + 8 * t);
    const float4 pb0 = *(const float4*)(yr0 + 8 * t + 4);
    const float4 pa1 = *(const float4*)(yr1 + 8 * t);
    const float4 pb1 = *(const float4*)(yr1 + 8 * t + 4);
    const float yb0[8] = {pa0.x, pa0.y, pa0.z, pa0.w, pb0.x, pb0.y, pb0.z, pb0.w};
    const float yb1[8] = {pa1.x, pa1.y, pa1.z, pa1.w, pb1.x, pb1.y, pb1.z, pb1.w};
    float xb0[8], xb1[8];

    #pragma unroll
    for (int kk = 0; kk < 8; ++kk) {
      xb0[kk] = x0;                    // pre-update local state
      xb1[kk] = x1;
      float a0 = 0.f, a1 = 0.f, b0 = 0.f, b1 = 0.f;
      #pragma unroll
      for (int j = 0; j < 64; j += 2) {
        const float s0 = bcast(x0, j);
        const float s1 = bcast(x1, j);
        const float u0 = bcast(x0, j + 1);
        const float u1 = bcast(x1, j + 1);
        a0 = fmaf(Mrow[j],     s0, a0);
        b0 = fmaf(Mrow[j],     s1, b0);
        a1 = fmaf(Mrow[j + 1], u0, a1);
        b1 = fmaf(Mrow[j + 1], u1, b1);
      }
      x0 = fmaf(Lg, yb0[kk], a0 + a1);
      x1 = fmaf(Lg, yb1[kk], b0 + b1);
    }
    *(float4*)(X0 + 8 * t)     = make_float4(xb0[0], xb0[1], xb0[2], xb0[3]);
    *(float4*)(X0 + 8 * t + 4) = make_float4(xb0[4], xb0[5], xb0[6], xb0[7]);
    *(float4*)(X1 + 8 * t)     = make_float4(xb1[0], xb1[1], xb1[2], xb1[3]);
    *(float4*)(X1 + 8 * t + 4) = make_float4(xb1[4], xb1[5], xb1[6], xb1[7]);
  }
  bb[c0 * 64 + lane] = x0;             // chunk-end local state (b_c)
  bb[c1 * 64 + lane] = x1;
}

// ------------------------------------------------------------------- zh ----
// Per chunk c (one wave): lookback -> s_c; doubling builds z[:][k]=M^k s_c
// in LDS (log depth, 6 steps); zcol = z + X_l column; out = H zcol in place.
__global__ __launch_bounds__(64, 2) void kf_zh(const float* __restrict__ Hm,
                                               const float* __restrict__ ws,
                                               const float* __restrict__ bb,
                                               float* xo, int Nv) {
  const int lane = threadIdx.x;
  const int c    = (int)blockIdx.x;
  __shared__ __align__(16) float z[64][68];   // pad 68: b128-aligned, write-conflict mild

  // ---- lookback: s = b[c-1] + P64*(b[c-2] + ... + P64*b[c-8]) (pad covers c<0)
  float s;
  {
    float Prow[64];
    #pragma unroll
    for (int j = 0; j < 64; j += 4) {
      const float4 p4 = *(const float4*)(ws + 6 * 4096 + lane * 64 + j);
      Prow[j + 0] = p4.x; Prow[j + 1] = p4.y;
      Prow[j + 2] = p4.z; Prow[j + 3] = p4.w;
    }
    s = bb[(c - LOOKBACK) * 64 + lane];
    #pragma unroll 1
    for (int t = LOOKBACK - 1; t >= 1; --t) {
      float a0 = 0.f, a1 = 0.f;
      #pragma unroll
      for (int j = 0; j < 64; j += 2) {
        a0 = fmaf(Prow[j],     bcast(s, j),     a0);
        a1 = fmaf(Prow[j + 1], bcast(s, j + 1), a1);
      }
      s = (a0 + a1) + bb[(c - t) * 64 + lane];
    }
  }

  z[lane][0] = s;
  __syncthreads();

  // ---- doubling: cols [w,2w) = M^w * cols [0,w), w = 1,2,4,8,16,32
  #pragma unroll 1
  for (int t = 0; t < 6; ++t) {
    float Mp[64];                                 // row `lane` of M^(2^t)
    #pragma unroll
    for (int j = 0; j < 64; j += 4) {
      const float4 m4 = *(const float4*)(ws + t * 4096 + lane * 64 + j);
      Mp[j + 0] = m4.x; Mp[j + 1] = m4.y;
      Mp[j + 2] = m4.z; Mp[j + 3] = m4.w;
    }
    const int w = 1 << t;
    if (w < 4) {
      #pragma unroll
      for (int k = 0; k < 2; ++k) {               // at most 2 cols (w=1 does k=0 only)
        if (k < w) {
          float a0 = 0.f, a1 = 0.f;
          #pragma unroll
          for (int j = 0; j < 64; j += 2) {
            a0 = fmaf(Mp[j],     z[j][k],     a0);
            a1 = fmaf(Mp[j + 1], z[j + 1][k], a1);
          }
          z[lane][k + w] = a0 + a1;               // writes [w,2w): disjoint from reads
        }
      }
    } else {
      #pragma unroll 1
      for (int k = 0; k < w; k += 4) {
        float a0 = 0.f, a1 = 0.f, a2 = 0.f, a3 = 0.f;
        #pragma unroll
        for (int j = 0; j < 64; ++j) {
          const float4 zv = *(const float4*)&z[j][k];   // broadcast b128
          const float  m  = Mp[j];
          a0 = fmaf(m, zv.x, a0);
          a1 = fmaf(m, zv.y, a1);
          a2 = fmaf(m, zv.z, a2);
          a3 = fmaf(m, zv.w, a3);
        }
        *(float4*)&z[lane][k + w] = make_float4(a0, a1, a2, a3);
      }
    }
    __syncthreads();
  }

  // ---- zcol[j] = z[j][lane] + X_l[j][c*64+lane]  (conflict-free LDS col +
  //      coalesced global reads); then out = H * zcol, coalesced in-place.
  float zcol[64];
  {
    const float* xc = xo + (size_t)c * CHUNK + lane;
    #pragma unroll 8
    for (int j = 0; j < 64; ++j) {
      zcol[j] = z[j][lane] + xc[(size_t)j * (size_t)Nv];
    }
  }

  float* oc = xo + (size_t)c * CHUNK + lane;
  #pragma unroll 1
  for (int r = 0; r < 64; ++r) {
    const float* hr = Hm + r * 64;                // wave-uniform -> scalar loads
    float a0 = 0.f, a1 = 0.f;
    #pragma unroll
    for (int j = 0; j < 64; j += 2) {
      a0 = fmaf(hr[j],     zcol[j],     a0);
      a1 = fmaf(hr[j + 1], zcol[j + 1], a1);
    }
    oc[(size_t)r * (size_t)Nv] = a0 + a1;
  }
}

// ---------------------------------------------------------------------------
extern "C" void kernel_launch(void* const* d_in, const int* in_sizes, int n_in,
                              void* d_out, int out_size, void* d_ws, size_t ws_size,
                              hipStream_t stream) {
  const float* y  = (const float*)d_in[0];
  const float* A  = (const float*)d_in[1];
  const float* Hm = (const float*)d_in[2];
  const float* Lp = (const float*)d_in[3];
  const int Nv = in_sizes[0] / 64;          // 200000 (multiple of 64)
  const int P  = (Nv + CHUNK - 1) / CHUNK;  // 3125

  float* ws = (float*)d_ws;
  float* bb = ws + 7 * 4096 + 512;          // after powers + zero pad

  kf_setup<<<1, 1024, 0, stream>>>(A, Hm, Lp, ws);
  kf_scan<<<(P + 1) / 2, 64, 0, stream>>>(y, A, Hm, Lp, bb, (float*)d_out, Nv, P);
  kf_zh<<<P, 64, 0, stream>>>(Hm, ws, bb, (float*)d_out, Nv);
}